// Round 1
// baseline (3962.464 us; speedup 1.0000x reference)
//
#include <hip/hip_runtime.h>
#include <hip/hip_bf16.h>
#include <cstdint>

// GRU scan: T=256, B=64, H=1024.
// Strategy: precompute gi = x@Wi + bi with one big bf16 MFMA GEMM, then a
// persistent 256-WG kernel walks the 256 sequential steps with Wh^T resident
// in LDS and group-local global barriers (4 groups x 64 WGs, 16 batches each).

#define TT 256
#define BB 64
#define HH 1024
#define H3 3072

typedef __attribute__((ext_vector_type(8))) short s16x8;
typedef __attribute__((ext_vector_type(4))) float f32x4;
typedef __attribute__((ext_vector_type(4))) unsigned int u32x4;

__device__ __forceinline__ float fast_sigmoid(float x) {
  float e = __expf(-fabsf(x));
  float s = 1.0f / (1.0f + e);
  return x >= 0.0f ? s : 1.0f - s;
}
__device__ __forceinline__ float fast_tanh(float x) {
  float e = __expf(-2.0f * fabsf(x));
  float t = (1.0f - e) / (1.0f + e);
  return x >= 0.0f ? t : -t;
}
__device__ __forceinline__ f32x4 mfma16(s16x8 a, s16x8 b, f32x4 c) {
  return __builtin_amdgcn_mfma_f32_16x16x32_bf16(a, b, c, 0, 0, 0);
}

// ---------------- conversion kernels ----------------

__global__ void k_cvt_x(const float* __restrict__ x, __hip_bfloat16* __restrict__ xb, int n) {
  int i = (blockIdx.x * blockDim.x + threadIdx.x) * 4;
  if (i + 3 < n) {
    float4 v = *reinterpret_cast<const float4*>(x + i);
    xb[i + 0] = __float2bfloat16(v.x);
    xb[i + 1] = __float2bfloat16(v.y);
    xb[i + 2] = __float2bfloat16(v.z);
    xb[i + 3] = __float2bfloat16(v.w);
  }
}

// W [1024][3072] f32 -> WT [3072][1024] bf16
__global__ void k_transpose_w(const float* __restrict__ W, __hip_bfloat16* __restrict__ WT) {
  __shared__ float tile[32][33];
  int c0 = blockIdx.x * 32, r0 = blockIdx.y * 32;
  int tx = threadIdx.x & 31, ty = threadIdx.x >> 5;  // 256 threads: 32x8
#pragma unroll
  for (int i = 0; i < 32; i += 8)
    tile[ty + i][tx] = W[(size_t)(r0 + ty + i) * H3 + c0 + tx];
  __syncthreads();
#pragma unroll
  for (int i = 0; i < 32; i += 8)
    WT[(size_t)(c0 + ty + i) * HH + r0 + tx] = __float2bfloat16(tile[tx][ty + i]);
}

// ---------------- gi = x @ Wi + bi  (bf16 MFMA, 128x128 tile, BK=32) ----------------

template <bool GIF32>
__global__ __launch_bounds__(256, 2) void k_gemm_gi(
    const __hip_bfloat16* __restrict__ A,   // [16384][1024] x bf16
    const __hip_bfloat16* __restrict__ Bt,  // [3072][1024]  Wi^T bf16
    const float* __restrict__ bi,           // [3072]
    void* __restrict__ gi)                  // [16384][3072] f32 or bf16
{
  __shared__ __align__(16) __hip_bfloat16 As[128 * 32];
  __shared__ __align__(16) __hip_bfloat16 Bs[128 * 32];
  const int bid = blockIdx.x;
  const int mt = bid / 24, nt = bid % 24;  // consecutive blocks share the A-tile; B panels stay L2-resident per XCD
  const int m0 = mt * 128, n0 = nt * 128;
  const int tid = threadIdx.x, lane = tid & 63, w = tid >> 6;
  const int wm = w & 1, wn = w >> 1;

  f32x4 acc[4][4];
#pragma unroll
  for (int ai = 0; ai < 4; ++ai)
#pragma unroll
    for (int bj = 0; bj < 4; ++bj) acc[ai][bj] = (f32x4){0.f, 0.f, 0.f, 0.f};

  for (int k0 = 0; k0 < HH; k0 += 32) {
#pragma unroll
    for (int i = 0; i < 2; ++i) {
      const int c = w + i * 4;          // 1KB chunk id, wave-uniform
      const int idx = c * 64 + lane;    // 16B unit id
      const int row = idx >> 2, slot = idx & 3;
      __builtin_amdgcn_global_load_lds(
          (const __attribute__((address_space(1))) void*)(A + (size_t)(m0 + row) * HH + k0 + slot * 8),
          (__attribute__((address_space(3))) void*)(As + c * 512), 16, 0, 0);
      __builtin_amdgcn_global_load_lds(
          (const __attribute__((address_space(1))) void*)(Bt + (size_t)(n0 + row) * HH + k0 + slot * 8),
          (__attribute__((address_space(3))) void*)(Bs + c * 512), 16, 0, 0);
    }
    __syncthreads();
    s16x8 af[4], bf[4];
#pragma unroll
    for (int ai = 0; ai < 4; ++ai) {
      int r = wm * 64 + ai * 16 + (lane & 15);
      af[ai] = *reinterpret_cast<const s16x8*>(As + r * 32 + (lane >> 4) * 8);
    }
#pragma unroll
    for (int bj = 0; bj < 4; ++bj) {
      int r = wn * 64 + bj * 16 + (lane & 15);
      bf[bj] = *reinterpret_cast<const s16x8*>(Bs + r * 32 + (lane >> 4) * 8);
    }
#pragma unroll
    for (int ai = 0; ai < 4; ++ai)
#pragma unroll
      for (int bj = 0; bj < 4; ++bj) acc[ai][bj] = mfma16(af[ai], bf[bj], acc[ai][bj]);
    __syncthreads();
  }

#pragma unroll
  for (int ai = 0; ai < 4; ++ai) {
#pragma unroll
    for (int reg = 0; reg < 4; ++reg) {
      const size_t row = (size_t)m0 + wm * 64 + ai * 16 + (lane >> 4) * 4 + reg;
#pragma unroll
      for (int bj = 0; bj < 4; ++bj) {
        const int col = n0 + wn * 64 + bj * 16 + (lane & 15);
        float v = acc[ai][bj][reg] + bi[col];
        if (GIF32)
          reinterpret_cast<float*>(gi)[row * H3 + col] = v;
        else
          reinterpret_cast<__hip_bfloat16*>(gi)[row * H3 + col] = __float2bfloat16(v);
      }
    }
  }
}

// ---------------- persistent step kernel ----------------

// group barrier: release stores -> arrive -> poll -> acquire (inv)
__device__ __forceinline__ void gbar(unsigned* c, unsigned target) {
  __builtin_amdgcn_fence(__ATOMIC_RELEASE, "agent");
  if (threadIdx.x == 0) {
    __hip_atomic_fetch_add(c, 1u, __ATOMIC_RELAXED, __HIP_MEMORY_SCOPE_AGENT);
    int guard = 0;
    while (__hip_atomic_load(c, __ATOMIC_RELAXED, __HIP_MEMORY_SCOPE_AGENT) < target &&
           ++guard < (1 << 21)) {
      __builtin_amdgcn_s_sleep(2);
    }
  }
  __builtin_amdgcn_fence(__ATOMIC_ACQUIRE, "agent");
}

// 256 WGs x 64 threads. 4 groups (16 batches each) x 64 WGs (16 j-cols each).
// Wh^T slice (48 cols x 1024 k, 96 KiB) LDS-resident with XOR swizzle.
template <bool GIF32>
__global__ __launch_bounds__(64, 1) void k_gru(
    const void* __restrict__ gi_,
    const int* __restrict__ resets,   // [256][64]
    const float* __restrict__ h0,     // [64][1024]
    const float* __restrict__ bn,     // [1024]
    const __hip_bfloat16* __restrict__ WhT,  // [3072][1024]
    __hip_bfloat16* hbuf,                    // [2][64][1024]
    float* __restrict__ out,                 // [64*1024 hfinal | 256*64*1024 ys]
    unsigned* cnt)                           // 4 counters, 128B apart
{
  __shared__ __align__(16) __hip_bfloat16 Bsh[48 * 1024];  // 96 KiB
  const int wg = blockIdx.x, lane = threadIdx.x;
  const int g = (wg & 7) >> 1;                    // XCD-pair -> group (perf heuristic only)
  const int s = ((wg >> 3) << 1) | (wg & 1);      // 0..63 within group
  const int bg0 = g * 16, j0 = s * 16;
  unsigned* mycnt = cnt + g * 32;

  // stage Wh^T slice into LDS, XOR-swizzled: data(row, slot16B) at byte
  // row*2048 + ((slot*16) ^ ((row&7)<<4))
  for (int cch = lane; cch < 48 * 128; cch += 64) {
    const int row = cch >> 7, slot = cch & 127;
    const int gate = row >> 4, jj = row & 15;
    u32x4 v = *reinterpret_cast<const u32x4*>(WhT + (size_t)(gate * HH + j0 + jj) * HH + slot * 8);
    const int byte = row * 2048 + ((slot * 16) ^ ((row & 7) << 4));
    *reinterpret_cast<u32x4*>(reinterpret_cast<char*>(Bsh) + byte) = v;
  }

  const int jl = lane & 15;         // local j (C col)
  const int bh = (lane >> 4) * 4;   // C row base (batch-local)
  float hp[4];
#pragma unroll
  for (int r = 0; r < 4; ++r) hp[r] = h0[(size_t)(bg0 + bh + r) * HH + j0 + jl];
  {
    __hip_bfloat16* h1 = hbuf + 65536;  // buffer 1 holds h_{-1}
#pragma unroll
    for (int r = 0; r < 4; ++r)
      h1[(size_t)(bg0 + bh + r) * HH + j0 + jl] = __float2bfloat16(hp[r]);
  }
  __syncthreads();
  gbar(mycnt, 64u);

  const int al = lane & 15;           // A-fragment batch row
  const int koff = (lane >> 4) * 8;   // A-fragment k sub-offset (elements)
  const char* bbase = reinterpret_cast<const char*>(Bsh);
  const int xsw = (jl & 7) << 4;
  const int rb0 = (0 * 16 + jl) * 2048, rb1 = (1 * 16 + jl) * 2048, rb2 = (2 * 16 + jl) * 2048;

  for (int t = 0; t < TT; ++t) {
    const __hip_bfloat16* rd = hbuf + ((t + 1) & 1) * 65536;
    __hip_bfloat16* wr = hbuf + (t & 1) * 65536;

    // prefetch elementwise operands early (overlap with MFMA chain)
    const int j = j0 + jl;
    const float bnj = bn[j];
    float gir[4], giz[4], gin[4];
    int rstE[4];
#pragma unroll
    for (int r = 0; r < 4; ++r) {
      const int b = bg0 + bh + r;
      rstE[r] = resets[t * BB + b];
      if (GIF32) {
        const float* grow = reinterpret_cast<const float*>(gi_) + (size_t)(t * BB + b) * H3;
        gir[r] = grow[j]; giz[r] = grow[HH + j]; gin[r] = grow[2 * HH + j];
      } else {
        const __hip_bfloat16* grow =
            reinterpret_cast<const __hip_bfloat16*>(gi_) + (size_t)(t * BB + b) * H3;
        gir[r] = __bfloat162float(grow[j]);
        giz[r] = __bfloat162float(grow[HH + j]);
        gin[r] = __bfloat162float(grow[2 * HH + j]);
      }
    }

    const int rstA = resets[t * BB + bg0 + al];
    f32x4 aR = {0.f, 0.f, 0.f, 0.f}, aZ = {0.f, 0.f, 0.f, 0.f}, aN = {0.f, 0.f, 0.f, 0.f};
    const char* arow = reinterpret_cast<const char*>(rd + (size_t)(bg0 + al) * HH + koff);
#pragma unroll
    for (int kk = 0; kk < 32; ++kk) {
      u32x4 av = *reinterpret_cast<const u32x4*>(arow + kk * 64);
      if (rstA) av = (u32x4){0u, 0u, 0u, 0u};
      s16x8 a = __builtin_bit_cast(s16x8, av);
      const int kb = kk * 64 + (lane >> 4) * 16;
      s16x8 b0 = *reinterpret_cast<const s16x8*>(bbase + rb0 + (kb ^ xsw));
      s16x8 b1 = *reinterpret_cast<const s16x8*>(bbase + rb1 + (kb ^ xsw));
      s16x8 b2 = *reinterpret_cast<const s16x8*>(bbase + rb2 + (kb ^ xsw));
      aR = mfma16(a, b0, aR);
      aZ = mfma16(a, b1, aZ);
      aN = mfma16(a, b2, aN);
    }

    float* ys = out + 65536 + (size_t)t * 65536;
#pragma unroll
    for (int r = 0; r < 4; ++r) {
      const int b = bg0 + bh + r;
      const float hprev = rstE[r] ? 0.f : hp[r];
      const float rg = fast_sigmoid(gir[r] + aR[r]);
      const float zg = fast_sigmoid(giz[r] + aZ[r]);
      const float ng = fast_tanh(gin[r] + rg * (aN[r] + bnj));
      const float hnew = (1.0f - zg) * ng + zg * hprev;
      ys[(size_t)b * HH + j] = hnew;
      wr[(size_t)b * HH + j] = __float2bfloat16(hnew);
      hp[r] = hnew;
    }
    gbar(mycnt, 64u * (t + 2));
  }

#pragma unroll
  for (int r = 0; r < 4; ++r)
    out[(size_t)(bg0 + bh + r) * HH + j0 + jl] = hp[r];
}

// ---------------- launch ----------------

extern "C" void kernel_launch(void* const* d_in, const int* in_sizes, int n_in,
                              void* d_out, int out_size, void* d_ws, size_t ws_size,
                              hipStream_t stream) {
  const float* x      = (const float*)d_in[0];  // [256,64,1024]
  const int* resets   = (const int*)d_in[1];    // [256,64]
  const float* h0     = (const float*)d_in[2];  // [64,1024]
  const float* Wi     = (const float*)d_in[3];  // [1024,3072]
  const float* bi     = (const float*)d_in[4];  // [3072]
  const float* Wh     = (const float*)d_in[5];  // [1024,3072]
  const float* bn     = (const float*)d_in[6];  // [1024]
  (void)in_sizes; (void)n_in; (void)out_size;

  char* ws = (char*)d_ws;
  __hip_bfloat16* xb   = (__hip_bfloat16*)(ws);             // 33554432 B
  __hip_bfloat16* WiT  = (__hip_bfloat16*)(ws + 33554432);  //  6291456 B
  __hip_bfloat16* WhT  = (__hip_bfloat16*)(ws + 39845888);  //  6291456 B
  __hip_bfloat16* hbuf = (__hip_bfloat16*)(ws + 46137344);  //   262144 B
  unsigned* cnt        = (unsigned*)(ws + 46399488);        //      512 B
  void* gi             = (void*)(ws + 46400000);

  const bool gif32 = ws_size >= 46400000ull + (size_t)16384 * 3072 * 4;

  hipMemsetAsync(cnt, 0, 512, stream);
  k_cvt_x<<<16384, 256, 0, stream>>>(x, xb, TT * BB * HH);
  k_transpose_w<<<dim3(96, 32), 256, 0, stream>>>(Wi, WiT);
  k_transpose_w<<<dim3(96, 32), 256, 0, stream>>>(Wh, WhT);
  if (gif32) {
    k_gemm_gi<true><<<3072, 256, 0, stream>>>(xb, WiT, bi, gi);
    k_gru<true><<<256, 64, 0, stream>>>(gi, resets, h0, bn, WhT, hbuf, (float*)d_out, cnt);
  } else {
    k_gemm_gi<false><<<3072, 256, 0, stream>>>(xb, WiT, bi, gi);
    k_gru<false><<<256, 64, 0, stream>>>(gi, resets, h0, bn, WhT, hbuf, (float*)d_out, cnt);
  }
}

// Round 2
// 2602.886 us; speedup vs baseline: 1.5223x; 1.5223x over previous
//
#include <hip/hip_runtime.h>
#include <hip/hip_bf16.h>
#include <cstdint>

// GRU scan: T=256, B=64, H=1024.
// gi = x@Wi + bi precomputed with one bf16 MFMA GEMM; then a persistent
// 256-WG kernel walks 256 sequential steps with Wh^T resident in LDS
// (96 KiB/WG, 64 WGs per group hold the full 6 MB Wh of that group's j-range).
// Cross-WG h exchange uses device-scope (coherent, L2-bypass) atomics and a
// fence-free per-WG-flag barrier: no fetch_add contention, no wbl2/inv.

#define TT 256
#define BB 64
#define HH 1024
#define H3 3072

typedef __attribute__((ext_vector_type(8))) short s16x8;
typedef __attribute__((ext_vector_type(4))) float f32x4;
typedef __attribute__((ext_vector_type(4))) unsigned int u32x4;
typedef unsigned long long ull;

__device__ __forceinline__ float fast_sigmoid(float x) {
  float e = __expf(-fabsf(x));
  float s = 1.0f / (1.0f + e);
  return x >= 0.0f ? s : 1.0f - s;
}
__device__ __forceinline__ float fast_tanh(float x) {
  float e = __expf(-2.0f * fabsf(x));
  float t = (1.0f - e) / (1.0f + e);
  return x >= 0.0f ? t : -t;
}
__device__ __forceinline__ f32x4 mfma16(s16x8 a, s16x8 b, f32x4 c) {
  return __builtin_amdgcn_mfma_f32_16x16x32_bf16(a, b, c, 0, 0, 0);
}

// ---------------- conversion kernels ----------------

__global__ void k_cvt_x(const float* __restrict__ x, __hip_bfloat16* __restrict__ xb, int n) {
  int i = (blockIdx.x * blockDim.x + threadIdx.x) * 4;
  if (i + 3 < n) {
    float4 v = *reinterpret_cast<const float4*>(x + i);
    xb[i + 0] = __float2bfloat16(v.x);
    xb[i + 1] = __float2bfloat16(v.y);
    xb[i + 2] = __float2bfloat16(v.z);
    xb[i + 3] = __float2bfloat16(v.w);
  }
}

// W [1024][3072] f32 -> WT [3072][1024] bf16
__global__ void k_transpose_w(const float* __restrict__ W, __hip_bfloat16* __restrict__ WT) {
  __shared__ float tile[32][33];
  int c0 = blockIdx.x * 32, r0 = blockIdx.y * 32;
  int tx = threadIdx.x & 31, ty = threadIdx.x >> 5;  // 256 threads: 32x8
#pragma unroll
  for (int i = 0; i < 32; i += 8)
    tile[ty + i][tx] = W[(size_t)(r0 + ty + i) * H3 + c0 + tx];
  __syncthreads();
#pragma unroll
  for (int i = 0; i < 32; i += 8)
    WT[(size_t)(c0 + ty + i) * HH + r0 + tx] = __float2bfloat16(tile[tx][ty + i]);
}

// ---------------- gi = x @ Wi + bi  (bf16 MFMA, 128x128 tile, BK=32) ----------------

template <bool GIF32>
__global__ __launch_bounds__(256, 2) void k_gemm_gi(
    const __hip_bfloat16* __restrict__ A,   // [16384][1024] x bf16
    const __hip_bfloat16* __restrict__ Bt,  // [3072][1024]  Wi^T bf16
    const float* __restrict__ bi,           // [3072]
    void* __restrict__ gi)                  // [16384][3072] f32 or bf16
{
  __shared__ __align__(16) __hip_bfloat16 As[128 * 32];
  __shared__ __align__(16) __hip_bfloat16 Bs[128 * 32];
  const int bid = blockIdx.x;
  const int mt = bid / 24, nt = bid % 24;
  const int m0 = mt * 128, n0 = nt * 128;
  const int tid = threadIdx.x, lane = tid & 63, w = tid >> 6;
  const int wm = w & 1, wn = w >> 1;

  f32x4 acc[4][4];
#pragma unroll
  for (int ai = 0; ai < 4; ++ai)
#pragma unroll
    for (int bj = 0; bj < 4; ++bj) acc[ai][bj] = (f32x4){0.f, 0.f, 0.f, 0.f};

  for (int k0 = 0; k0 < HH; k0 += 32) {
#pragma unroll
    for (int i = 0; i < 2; ++i) {
      const int c = w + i * 4;          // 1KB chunk id, wave-uniform
      const int idx = c * 64 + lane;    // 16B unit id
      const int row = idx >> 2, slot = idx & 3;
      __builtin_amdgcn_global_load_lds(
          (const __attribute__((address_space(1))) void*)(A + (size_t)(m0 + row) * HH + k0 + slot * 8),
          (__attribute__((address_space(3))) void*)(As + c * 512), 16, 0, 0);
      __builtin_amdgcn_global_load_lds(
          (const __attribute__((address_space(1))) void*)(Bt + (size_t)(n0 + row) * HH + k0 + slot * 8),
          (__attribute__((address_space(3))) void*)(Bs + c * 512), 16, 0, 0);
    }
    __syncthreads();
    s16x8 af[4], bf[4];
#pragma unroll
    for (int ai = 0; ai < 4; ++ai) {
      int r = wm * 64 + ai * 16 + (lane & 15);
      af[ai] = *reinterpret_cast<const s16x8*>(As + r * 32 + (lane >> 4) * 8);
    }
#pragma unroll
    for (int bj = 0; bj < 4; ++bj) {
      int r = wn * 64 + bj * 16 + (lane & 15);
      bf[bj] = *reinterpret_cast<const s16x8*>(Bs + r * 32 + (lane >> 4) * 8);
    }
#pragma unroll
    for (int ai = 0; ai < 4; ++ai)
#pragma unroll
      for (int bj = 0; bj < 4; ++bj) acc[ai][bj] = mfma16(af[ai], bf[bj], acc[ai][bj]);
    __syncthreads();
  }

#pragma unroll
  for (int ai = 0; ai < 4; ++ai) {
#pragma unroll
    for (int reg = 0; reg < 4; ++reg) {
      const size_t row = (size_t)m0 + wm * 64 + ai * 16 + (lane >> 4) * 4 + reg;
#pragma unroll
      for (int bj = 0; bj < 4; ++bj) {
        const int col = n0 + wn * 64 + bj * 16 + (lane & 15);
        float v = acc[ai][bj][reg] + bi[col];
        if (GIF32)
          reinterpret_cast<float*>(gi)[row * H3 + col] = v;
        else
          reinterpret_cast<__hip_bfloat16*>(gi)[row * H3 + col] = __float2bfloat16(v);
      }
    }
  }
}

// ---------------- persistent step kernel ----------------

// device-scope coherent store of one bf16 (bypasses non-coherent L2s)
__device__ __forceinline__ void st_h(__hip_bfloat16* p, float v) {
  unsigned short u = __builtin_bit_cast(unsigned short, __float2bfloat16(v));
  __hip_atomic_store(reinterpret_cast<unsigned short*>(p), u,
                     __ATOMIC_RELAXED, __HIP_MEMORY_SCOPE_AGENT);
}

// fence-free group barrier wait: lane i polls WG i's flag; no RMW, no inv.
__device__ __forceinline__ void gwait(unsigned* gf, unsigned target) {
  unsigned v;
  int guard = 0;
  do {
    v = __hip_atomic_load(gf + threadIdx.x, __ATOMIC_RELAXED, __HIP_MEMORY_SCOPE_AGENT);
  } while (__any(v < target) && ++guard < (1 << 20));
}

// 256 WGs x 64 threads. 4 groups (16 batches each) x 64 WGs (16 j-cols each).
// Wh^T slice (48 cols x 1024 k, 96 KiB) LDS-resident with XOR swizzle.
template <bool GIF32>
__global__ __launch_bounds__(64, 1) void k_gru(
    const void* __restrict__ gi_,
    const int* __restrict__ resets,   // [256][64]
    const float* __restrict__ h0,     // [64][1024]
    const float* __restrict__ bn,     // [1024]
    const __hip_bfloat16* __restrict__ WhT,  // [3072][1024]
    __hip_bfloat16* hbuf,                    // [2][64][1024]
    float* __restrict__ out,                 // [64*1024 hfinal | 256*64*1024 ys]
    unsigned* flags)                         // [4][64] publication counters
{
  __shared__ __align__(16) __hip_bfloat16 Bsh[48 * 1024];  // 96 KiB
  const int wg = blockIdx.x, lane = threadIdx.x;
  const int g = (wg & 7) >> 1;                // XCD-pair -> group (perf heuristic only)
  const int s = ((wg >> 3) << 1) | (wg & 1);  // 0..63 within group
  const int bg0 = g * 16, j0 = s * 16;
  unsigned* gf = flags + g * 64;

  // stage Wh^T slice into LDS, XOR-swizzled: data(row, slot16B) at byte
  // row*2048 + ((slot*16) ^ ((row&7)<<4))
  for (int cch = lane; cch < 48 * 128; cch += 64) {
    const int row = cch >> 7, slot = cch & 127;
    const int gate = row >> 4, jj = row & 15;
    u32x4 v = *reinterpret_cast<const u32x4*>(WhT + (size_t)(gate * HH + j0 + jj) * HH + slot * 8);
    const int byte = row * 2048 + ((slot * 16) ^ ((row & 7) << 4));
    *reinterpret_cast<u32x4*>(reinterpret_cast<char*>(Bsh) + byte) = v;
  }

  const int jl = lane & 15;         // local j (C col)
  const int bh = (lane >> 4) * 4;   // C row base (batch-local)
  float hp[4];
#pragma unroll
  for (int r = 0; r < 4; ++r) hp[r] = h0[(size_t)(bg0 + bh + r) * HH + j0 + jl];
  {
    __hip_bfloat16* h1 = hbuf + 65536;  // buffer 1 holds h_{-1}
#pragma unroll
    for (int r = 0; r < 4; ++r)
      st_h(&h1[(size_t)(bg0 + bh + r) * HH + j0 + jl], hp[r]);
  }
  asm volatile("s_waitcnt vmcnt(0)" ::: "memory");
  if (lane == 0)
    __hip_atomic_store(gf + s, 1u, __ATOMIC_RELAXED, __HIP_MEMORY_SCOPE_AGENT);
  __syncthreads();

  const int al = lane & 15;           // A-fragment batch row
  const int koff = (lane >> 4) * 8;   // A-fragment k sub-offset (elements)
  const char* bbase = reinterpret_cast<const char*>(Bsh);
  const int xsw = (jl & 7) << 4;
  const int rb0 = jl * 2048, rb1 = (16 + jl) * 2048, rb2 = (32 + jl) * 2048;
  const int j = j0 + jl;
  const float bnj = bn[j];

  for (int t = 0; t < TT; ++t) {
    // barrier-independent loads first: their latency hides under the poll
    float gir[4], giz[4], gin[4];
    int rstE[4];
#pragma unroll
    for (int r = 0; r < 4; ++r) {
      const int b = bg0 + bh + r;
      rstE[r] = resets[t * BB + b];
      if (GIF32) {
        const float* grow = reinterpret_cast<const float*>(gi_) + (size_t)(t * BB + b) * H3;
        gir[r] = grow[j]; giz[r] = grow[HH + j]; gin[r] = grow[2 * HH + j];
      } else {
        const __hip_bfloat16* grow =
            reinterpret_cast<const __hip_bfloat16*>(gi_) + (size_t)(t * BB + b) * H3;
        gir[r] = __bfloat162float(grow[j]);
        giz[r] = __bfloat162float(grow[HH + j]);
        gin[r] = __bfloat162float(grow[2 * HH + j]);
      }
    }
    const int rstA = resets[t * BB + bg0 + al];
    const ull amask = rstA ? 0ull : ~0ull;

    gwait(gf, (unsigned)(t + 1));  // all WGs published h_{t-1}

    const __hip_bfloat16* rd = hbuf + ((t + 1) & 1) * 65536;
    __hip_bfloat16* wr = hbuf + (t & 1) * 65536;

    f32x4 aR = {0.f, 0.f, 0.f, 0.f}, aZ = {0.f, 0.f, 0.f, 0.f}, aN = {0.f, 0.f, 0.f, 0.f};
    const ull* arow = reinterpret_cast<const ull*>(rd + (size_t)(bg0 + al) * HH + koff);
#pragma unroll
    for (int kk = 0; kk < 32; ++kk) {
      ull lo = __hip_atomic_load(arow + kk * 8 + 0, __ATOMIC_RELAXED, __HIP_MEMORY_SCOPE_AGENT);
      ull hi = __hip_atomic_load(arow + kk * 8 + 1, __ATOMIC_RELAXED, __HIP_MEMORY_SCOPE_AGENT);
      union { ull q[2]; s16x8 v; } u;
      u.q[0] = lo & amask;
      u.q[1] = hi & amask;
      const int kb = kk * 64 + (lane >> 4) * 16;
      s16x8 b0 = *reinterpret_cast<const s16x8*>(bbase + rb0 + (kb ^ xsw));
      s16x8 b1 = *reinterpret_cast<const s16x8*>(bbase + rb1 + (kb ^ xsw));
      s16x8 b2 = *reinterpret_cast<const s16x8*>(bbase + rb2 + (kb ^ xsw));
      aR = mfma16(u.v, b0, aR);
      aZ = mfma16(u.v, b1, aZ);
      aN = mfma16(u.v, b2, aN);
    }

    float hnew[4];
#pragma unroll
    for (int r = 0; r < 4; ++r) {
      const float hprev = rstE[r] ? 0.f : hp[r];
      const float rg = fast_sigmoid(gir[r] + aR[r]);
      const float zg = fast_sigmoid(giz[r] + aZ[r]);
      const float ng = fast_tanh(gin[r] + rg * (aN[r] + bnj));
      hnew[r] = (1.0f - zg) * ng + zg * hprev;
      st_h(&wr[(size_t)(bg0 + bh + r) * HH + j], hnew[r]);
      hp[r] = hnew[r];
    }
    asm volatile("s_waitcnt vmcnt(0)" ::: "memory");  // h stores globally visible
    if (lane == 0)
      __hip_atomic_store(gf + s, (unsigned)(t + 2), __ATOMIC_RELAXED, __HIP_MEMORY_SCOPE_AGENT);

    // ys writes after the flag: off the inter-WG critical path
    float* ys = out + 65536 + (size_t)t * 65536;
#pragma unroll
    for (int r = 0; r < 4; ++r)
      __builtin_nontemporal_store(hnew[r], &ys[(size_t)(bg0 + bh + r) * HH + j]);
  }

#pragma unroll
  for (int r = 0; r < 4; ++r)
    out[(size_t)(bg0 + bh + r) * HH + j0 + jl] = hp[r];
}

// ---------------- launch ----------------

extern "C" void kernel_launch(void* const* d_in, const int* in_sizes, int n_in,
                              void* d_out, int out_size, void* d_ws, size_t ws_size,
                              hipStream_t stream) {
  const float* x      = (const float*)d_in[0];  // [256,64,1024]
  const int* resets   = (const int*)d_in[1];    // [256,64]
  const float* h0     = (const float*)d_in[2];  // [64,1024]
  const float* Wi     = (const float*)d_in[3];  // [1024,3072]
  const float* bi     = (const float*)d_in[4];  // [3072]
  const float* Wh     = (const float*)d_in[5];  // [1024,3072]
  const float* bn     = (const float*)d_in[6];  // [1024]
  (void)in_sizes; (void)n_in; (void)out_size;

  char* ws = (char*)d_ws;
  __hip_bfloat16* xb   = (__hip_bfloat16*)(ws);             // 33554432 B
  __hip_bfloat16* WiT  = (__hip_bfloat16*)(ws + 33554432);  //  6291456 B
  __hip_bfloat16* WhT  = (__hip_bfloat16*)(ws + 39845888);  //  6291456 B
  __hip_bfloat16* hbuf = (__hip_bfloat16*)(ws + 46137344);  //   262144 B
  unsigned* flags      = (unsigned*)(ws + 46399488);        //     1024 B
  void* gi             = (void*)(ws + 46400512);

  const bool gif32 = ws_size >= 46400512ull + (size_t)16384 * 3072 * 4;

  hipMemsetAsync(flags, 0, 1024, stream);
  k_cvt_x<<<16384, 256, 0, stream>>>(x, xb, TT * BB * HH);
  k_transpose_w<<<dim3(96, 32), 256, 0, stream>>>(Wi, WiT);
  k_transpose_w<<<dim3(96, 32), 256, 0, stream>>>(Wh, WhT);
  if (gif32) {
    k_gemm_gi<true><<<3072, 256, 0, stream>>>(xb, WiT, bi, gi);
    k_gru<true><<<256, 64, 0, stream>>>(gi, resets, h0, bn, WhT, hbuf, (float*)d_out, flags);
  } else {
    k_gemm_gi<false><<<3072, 256, 0, stream>>>(xb, WiT, bi, gi);
    k_gru<false><<<256, 64, 0, stream>>>(gi, resets, h0, bn, WhT, hbuf, (float*)d_out, flags);
  }
}

// Round 3
// 1894.372 us; speedup vs baseline: 2.0917x; 1.3740x over previous
//
#include <hip/hip_runtime.h>
#include <hip/hip_bf16.h>
#include <cstdint>

// GRU scan: T=256, B=64, H=1024.
// gi = x@Wi + bi precomputed with one bf16 MFMA GEMM; then a persistent
// 256-WG kernel walks 256 sequential steps with Wh^T resident in LDS.
// Cross-WG h exchange: NO barrier, NO flags. h_t for each step goes to a
// fresh slot of a [257][4][16][1024] bf16 sequence buffer (sentinel-filled
// 0xFF). Writers publish coalesced 8B agent-scope atomic stores; readers
// poll-load their words and retry while any word is still the sentinel
// (0xFFFF... = all -NaN bf16, unproducible by finite GRU arithmetic).

#define TT 256
#define BB 64
#define HH 1024
#define H3 3072

typedef __attribute__((ext_vector_type(8))) short s16x8;
typedef __attribute__((ext_vector_type(4))) float f32x4;
typedef __attribute__((ext_vector_type(4))) unsigned int u32x4;
typedef unsigned long long ull;

__device__ __forceinline__ float fast_sigmoid(float x) {
  float e = __expf(-fabsf(x));
  float s = 1.0f / (1.0f + e);
  return x >= 0.0f ? s : 1.0f - s;
}
__device__ __forceinline__ float fast_tanh(float x) {
  float e = __expf(-2.0f * fabsf(x));
  float t = (1.0f - e) / (1.0f + e);
  return x >= 0.0f ? t : -t;
}
__device__ __forceinline__ f32x4 mfma16(s16x8 a, s16x8 b, f32x4 c) {
  return __builtin_amdgcn_mfma_f32_16x16x32_bf16(a, b, c, 0, 0, 0);
}

// ---------------- conversion kernels ----------------

__global__ void k_cvt_x(const float* __restrict__ x, __hip_bfloat16* __restrict__ xb, int n) {
  int i = (blockIdx.x * blockDim.x + threadIdx.x) * 4;
  if (i + 3 < n) {
    float4 v = *reinterpret_cast<const float4*>(x + i);
    xb[i + 0] = __float2bfloat16(v.x);
    xb[i + 1] = __float2bfloat16(v.y);
    xb[i + 2] = __float2bfloat16(v.z);
    xb[i + 3] = __float2bfloat16(v.w);
  }
}

// W [1024][3072] f32 -> WT [3072][1024] bf16
__global__ void k_transpose_w(const float* __restrict__ W, __hip_bfloat16* __restrict__ WT) {
  __shared__ float tile[32][33];
  int c0 = blockIdx.x * 32, r0 = blockIdx.y * 32;
  int tx = threadIdx.x & 31, ty = threadIdx.x >> 5;  // 256 threads: 32x8
#pragma unroll
  for (int i = 0; i < 32; i += 8)
    tile[ty + i][tx] = W[(size_t)(r0 + ty + i) * H3 + c0 + tx];
  __syncthreads();
#pragma unroll
  for (int i = 0; i < 32; i += 8)
    WT[(size_t)(c0 + ty + i) * HH + r0 + tx] = __float2bfloat16(tile[tx][ty + i]);
}

// ---------------- gi = x @ Wi + bi  (bf16 MFMA, 128x128 tile, BK=32) ----------------

template <bool GIF32>
__global__ __launch_bounds__(256, 2) void k_gemm_gi(
    const __hip_bfloat16* __restrict__ A,   // [16384][1024] x bf16
    const __hip_bfloat16* __restrict__ Bt,  // [3072][1024]  Wi^T bf16
    const float* __restrict__ bi,           // [3072]
    void* __restrict__ gi)                  // [16384][3072] f32 or bf16
{
  __shared__ __align__(16) __hip_bfloat16 As[128 * 32];
  __shared__ __align__(16) __hip_bfloat16 Bs[128 * 32];
  const int bid = blockIdx.x;
  const int mt = bid / 24, nt = bid % 24;
  const int m0 = mt * 128, n0 = nt * 128;
  const int tid = threadIdx.x, lane = tid & 63, w = tid >> 6;
  const int wm = w & 1, wn = w >> 1;

  f32x4 acc[4][4];
#pragma unroll
  for (int ai = 0; ai < 4; ++ai)
#pragma unroll
    for (int bj = 0; bj < 4; ++bj) acc[ai][bj] = (f32x4){0.f, 0.f, 0.f, 0.f};

  for (int k0 = 0; k0 < HH; k0 += 32) {
#pragma unroll
    for (int i = 0; i < 2; ++i) {
      const int c = w + i * 4;          // 1KB chunk id, wave-uniform
      const int idx = c * 64 + lane;    // 16B unit id
      const int row = idx >> 2, slot = idx & 3;
      __builtin_amdgcn_global_load_lds(
          (const __attribute__((address_space(1))) void*)(A + (size_t)(m0 + row) * HH + k0 + slot * 8),
          (__attribute__((address_space(3))) void*)(As + c * 512), 16, 0, 0);
      __builtin_amdgcn_global_load_lds(
          (const __attribute__((address_space(1))) void*)(Bt + (size_t)(n0 + row) * HH + k0 + slot * 8),
          (__attribute__((address_space(3))) void*)(Bs + c * 512), 16, 0, 0);
    }
    __syncthreads();
    s16x8 af[4], bf[4];
#pragma unroll
    for (int ai = 0; ai < 4; ++ai) {
      int r = wm * 64 + ai * 16 + (lane & 15);
      af[ai] = *reinterpret_cast<const s16x8*>(As + r * 32 + (lane >> 4) * 8);
    }
#pragma unroll
    for (int bj = 0; bj < 4; ++bj) {
      int r = wn * 64 + bj * 16 + (lane & 15);
      bf[bj] = *reinterpret_cast<const s16x8*>(Bs + r * 32 + (lane >> 4) * 8);
    }
#pragma unroll
    for (int ai = 0; ai < 4; ++ai)
#pragma unroll
      for (int bj = 0; bj < 4; ++bj) acc[ai][bj] = mfma16(af[ai], bf[bj], acc[ai][bj]);
    __syncthreads();
  }

#pragma unroll
  for (int ai = 0; ai < 4; ++ai) {
#pragma unroll
    for (int reg = 0; reg < 4; ++reg) {
      const size_t row = (size_t)m0 + wm * 64 + ai * 16 + (lane >> 4) * 4 + reg;
#pragma unroll
      for (int bj = 0; bj < 4; ++bj) {
        const int col = n0 + wn * 64 + bj * 16 + (lane & 15);
        float v = acc[ai][bj][reg] + bi[col];
        if (GIF32)
          reinterpret_cast<float*>(gi)[row * H3 + col] = v;
        else
          reinterpret_cast<__hip_bfloat16*>(gi)[row * H3 + col] = __float2bfloat16(v);
      }
    }
  }
}

// ---------------- persistent step kernel ----------------

// 256 WGs x 64 threads. 4 groups (16 batches each) x 64 WGs (16 j-cols each).
// Wh^T slice (48 cols x 1024 k, 96 KiB) LDS-resident with XOR swizzle.
template <bool GIF32>
__global__ __launch_bounds__(64, 1) void k_gru(
    const void* __restrict__ gi_,
    const int* __restrict__ resets,   // [256][64]
    const float* __restrict__ h0,     // [64][1024]
    const float* __restrict__ bn,     // [1024]
    const __hip_bfloat16* __restrict__ WhT,  // [3072][1024]
    __hip_bfloat16* hseq,                    // [257][4][16][1024] sentinel-filled
    float* __restrict__ out)                 // [64*1024 hfinal | 256*64*1024 ys]
{
  __shared__ __align__(16) __hip_bfloat16 Bsh[48 * 1024];  // 96 KiB
  __shared__ __align__(8) __hip_bfloat16 hsh[16][16];      // 512 B transpose buffer
  const int wg = blockIdx.x, lane = threadIdx.x;
  const int g = (wg & 7) >> 1;                // XCD-pair -> group (perf heuristic only)
  const int s = ((wg >> 3) << 1) | (wg & 1);  // 0..63 within group
  const int bg0 = g * 16, j0 = s * 16;

  // stage Wh^T slice into LDS, XOR-swizzled: data(row, slot16B) at byte
  // row*2048 + ((slot*16) ^ ((row&7)<<4))
  for (int cch = lane; cch < 48 * 128; cch += 64) {
    const int row = cch >> 7, slot = cch & 127;
    const int gate = row >> 4, jj = row & 15;
    u32x4 v = *reinterpret_cast<const u32x4*>(WhT + (size_t)(gate * HH + j0 + jj) * HH + slot * 8);
    const int byte = row * 2048 + ((slot * 16) ^ ((row & 7) << 4));
    *reinterpret_cast<u32x4*>(reinterpret_cast<char*>(Bsh) + byte) = v;
  }

  const int jl = lane & 15;         // local j (C col)
  const int bh = (lane >> 4) * 4;   // C row base (batch-local)
  const int prow = lane >> 2, pq = (lane & 3) * 4;  // publish layout: 8B per lane

  float hp[4];
#pragma unroll
  for (int r = 0; r < 4; ++r) hp[r] = h0[(size_t)(bg0 + bh + r) * HH + j0 + jl];

  // publish slot 0 (= h_{-1}): LDS transpose -> coalesced 8B atomic stores
#pragma unroll
  for (int r = 0; r < 4; ++r) hsh[bh + r][jl] = __float2bfloat16(hp[r]);
  __syncthreads();
  {
    ull pv = *reinterpret_cast<const ull*>(&hsh[prow][pq]);
    __hip_atomic_store(reinterpret_cast<ull*>(hseq + (size_t)g * 16384 + prow * HH + j0 + pq),
                       pv, __ATOMIC_RELAXED, __HIP_MEMORY_SCOPE_AGENT);
  }

  const int al = lane & 15;           // A-fragment batch row (group-local)
  const int koff = (lane >> 4) * 8;   // A-fragment k sub-offset (elements)
  const char* bbase = reinterpret_cast<const char*>(Bsh);
  const int xsw = (jl & 7) << 4;
  const int rb0 = jl * 2048, rb1 = (16 + jl) * 2048, rb2 = (32 + jl) * 2048;
  const int j = j0 + jl;
  const float bnj = bn[j];

  for (int t = 0; t < TT; ++t) {
    // barrier-independent cached loads first: latency hides under the poll
    float gir[4], giz[4], gin[4];
    int rstE[4];
#pragma unroll
    for (int r = 0; r < 4; ++r) {
      const int b = bg0 + bh + r;
      rstE[r] = resets[t * BB + b];
      if (GIF32) {
        const float* grow = reinterpret_cast<const float*>(gi_) + (size_t)(t * BB + b) * H3;
        gir[r] = grow[j]; giz[r] = grow[HH + j]; gin[r] = grow[2 * HH + j];
      } else {
        const __hip_bfloat16* grow =
            reinterpret_cast<const __hip_bfloat16*>(gi_) + (size_t)(t * BB + b) * H3;
        gir[r] = __bfloat162float(grow[j]);
        giz[r] = __bfloat162float(grow[HH + j]);
        gin[r] = __bfloat162float(grow[2 * HH + j]);
      }
    }
    const int rstA = resets[t * BB + bg0 + al];
    const ull amask = rstA ? 0ull : ~0ull;

    // poll-load h_{t-1}: retry while any word still sentinel
    const __hip_bfloat16* rd = hseq + (size_t)t * 65536 + g * 16384;
    const ull* arow = reinterpret_cast<const ull*>(rd + al * HH + koff);
    ull w[64];
    int guard = 0;
    bool ok;
    do {
#pragma unroll
      for (int kk = 0; kk < 32; ++kk) {
        w[2 * kk + 0] = __hip_atomic_load(arow + kk * 8 + 0, __ATOMIC_RELAXED, __HIP_MEMORY_SCOPE_AGENT);
        w[2 * kk + 1] = __hip_atomic_load(arow + kk * 8 + 1, __ATOMIC_RELAXED, __HIP_MEMORY_SCOPE_AGENT);
      }
      unsigned bad = 0;
#pragma unroll
      for (int i = 0; i < 64; ++i) bad |= (unsigned)(w[i] == ~0ull);
      ok = !__any((int)bad);
    } while (!ok && ++guard < (1 << 20));

    f32x4 aR = {0.f, 0.f, 0.f, 0.f}, aZ = {0.f, 0.f, 0.f, 0.f}, aN = {0.f, 0.f, 0.f, 0.f};
#pragma unroll
    for (int kk = 0; kk < 32; ++kk) {
      union { ull q[2]; s16x8 v; } u;
      u.q[0] = w[2 * kk + 0] & amask;
      u.q[1] = w[2 * kk + 1] & amask;
      const int kb = kk * 64 + (lane >> 4) * 16;
      s16x8 b0 = *reinterpret_cast<const s16x8*>(bbase + rb0 + (kb ^ xsw));
      s16x8 b1 = *reinterpret_cast<const s16x8*>(bbase + rb1 + (kb ^ xsw));
      s16x8 b2 = *reinterpret_cast<const s16x8*>(bbase + rb2 + (kb ^ xsw));
      aR = mfma16(u.v, b0, aR);
      aZ = mfma16(u.v, b1, aZ);
      aN = mfma16(u.v, b2, aN);
    }

    float hnew[4];
#pragma unroll
    for (int r = 0; r < 4; ++r) {
      const float hprev = rstE[r] ? 0.f : hp[r];
      const float rg = fast_sigmoid(gir[r] + aR[r]);
      const float zg = fast_sigmoid(giz[r] + aZ[r]);
      const float ng = fast_tanh(gin[r] + rg * (aN[r] + bnj));
      hnew[r] = (1.0f - zg) * ng + zg * hprev;
      hp[r] = hnew[r];
    }

    // publish h_t to slot t+1: LDS transpose -> coalesced 8B atomic stores
    __syncthreads();  // hsh free (previous read done)
#pragma unroll
    for (int r = 0; r < 4; ++r) hsh[bh + r][jl] = __float2bfloat16(hnew[r]);
    __syncthreads();
    {
      ull pv = *reinterpret_cast<const ull*>(&hsh[prow][pq]);
      __hip_atomic_store(
          reinterpret_cast<ull*>(hseq + (size_t)(t + 1) * 65536 + g * 16384 + prow * HH + j0 + pq),
          pv, __ATOMIC_RELAXED, __HIP_MEMORY_SCOPE_AGENT);
    }

    // ys writes after the publish: off the inter-WG critical path
    float* ys = out + 65536 + (size_t)t * 65536;
#pragma unroll
    for (int r = 0; r < 4; ++r)
      __builtin_nontemporal_store(hnew[r], &ys[(size_t)(bg0 + bh + r) * HH + j]);
  }

#pragma unroll
  for (int r = 0; r < 4; ++r)
    out[(size_t)(bg0 + bh + r) * HH + j0 + jl] = hp[r];
}

// ---------------- launch ----------------

extern "C" void kernel_launch(void* const* d_in, const int* in_sizes, int n_in,
                              void* d_out, int out_size, void* d_ws, size_t ws_size,
                              hipStream_t stream) {
  const float* x      = (const float*)d_in[0];  // [256,64,1024]
  const int* resets   = (const int*)d_in[1];    // [256,64]
  const float* h0     = (const float*)d_in[2];  // [64,1024]
  const float* Wi     = (const float*)d_in[3];  // [1024,3072]
  const float* bi     = (const float*)d_in[4];  // [3072]
  const float* Wh     = (const float*)d_in[5];  // [1024,3072]
  const float* bn     = (const float*)d_in[6];  // [1024]
  (void)in_sizes; (void)n_in; (void)out_size;

  char* ws = (char*)d_ws;
  // region0: xb [16384][1024] bf16 (33,554,432 B), dead after gemm, then
  //          reused as hseq [257][4][16][1024] bf16 (33,685,504 B)
  __hip_bfloat16* xb   = (__hip_bfloat16*)(ws);
  __hip_bfloat16* hseq = (__hip_bfloat16*)(ws);
  __hip_bfloat16* WiT  = (__hip_bfloat16*)(ws + 33685504);  // 6,291,456 B
  __hip_bfloat16* WhT  = (__hip_bfloat16*)(ws + 39976960);  // 6,291,456 B
  void* gi             = (void*)(ws + 46268416);

  const bool gif32 = ws_size >= 46268416ull + (size_t)16384 * 3072 * 4;

  k_cvt_x<<<16384, 256, 0, stream>>>(x, xb, TT * BB * HH);
  k_transpose_w<<<dim3(96, 32), 256, 0, stream>>>(Wi, WiT);
  k_transpose_w<<<dim3(96, 32), 256, 0, stream>>>(Wh, WhT);
  if (gif32) {
    k_gemm_gi<true><<<3072, 256, 0, stream>>>(xb, WiT, bi, gi);
    // xb dead; sentinel-fill hseq (0xFF = -NaN bf16 words)
    hipMemsetAsync(hseq, 0xFF, 33685504, stream);
    k_gru<true><<<256, 64, 0, stream>>>(gi, resets, h0, bn, WhT, hseq, (float*)d_out);
  } else {
    k_gemm_gi<false><<<3072, 256, 0, stream>>>(xb, WiT, bi, gi);
    hipMemsetAsync(hseq, 0xFF, 33685504, stream);
    k_gru<false><<<256, 64, 0, stream>>>(gi, resets, h0, bn, WhT, hseq, (float*)d_out);
  }
}

// Round 4
// 1591.751 us; speedup vs baseline: 2.4894x; 1.1901x over previous
//
#include <hip/hip_runtime.h>
#include <hip/hip_bf16.h>
#include <cstdint>

// GRU scan: T=256, B=64, H=1024.
// gi = x@Wi + bi precomputed with one bf16 MFMA GEMM; then a persistent
// 256-WG kernel walks 256 sequential steps with Wh^T resident in LDS.
// Cross-WG h exchange: NO barrier, NO flags. h_t goes to a fresh slot of a
// [257][4][16][1024] bf16 sequence buffer (sentinel 0xFF). Writers publish
// coalesced 8B agent-scope stores; readers poll chunks of 16 words (32 VGPRs,
// software-pipelined 2-deep) and retry a chunk while any word is sentinel
// (0xFFFF... = -NaN bf16 x4, unproducible by finite GRU arithmetic).

#define TT 256
#define BB 64
#define HH 1024
#define H3 3072

typedef __attribute__((ext_vector_type(8))) short s16x8;
typedef __attribute__((ext_vector_type(4))) float f32x4;
typedef __attribute__((ext_vector_type(4))) unsigned int u32x4;
typedef unsigned long long ull;

__device__ __forceinline__ float fast_sigmoid(float x) {
  float e = __expf(-fabsf(x));
  float s = 1.0f / (1.0f + e);
  return x >= 0.0f ? s : 1.0f - s;
}
__device__ __forceinline__ float fast_tanh(float x) {
  float e = __expf(-2.0f * fabsf(x));
  float t = (1.0f - e) / (1.0f + e);
  return x >= 0.0f ? t : -t;
}
__device__ __forceinline__ f32x4 mfma16(s16x8 a, s16x8 b, f32x4 c) {
  return __builtin_amdgcn_mfma_f32_16x16x32_bf16(a, b, c, 0, 0, 0);
}

// ---------------- conversion kernels ----------------

__global__ void k_cvt_x(const float* __restrict__ x, __hip_bfloat16* __restrict__ xb, int n) {
  int i = (blockIdx.x * blockDim.x + threadIdx.x) * 4;
  if (i + 3 < n) {
    float4 v = *reinterpret_cast<const float4*>(x + i);
    xb[i + 0] = __float2bfloat16(v.x);
    xb[i + 1] = __float2bfloat16(v.y);
    xb[i + 2] = __float2bfloat16(v.z);
    xb[i + 3] = __float2bfloat16(v.w);
  }
}

// W [1024][3072] f32 -> WT [3072][1024] bf16
__global__ void k_transpose_w(const float* __restrict__ W, __hip_bfloat16* __restrict__ WT) {
  __shared__ float tile[32][33];
  int c0 = blockIdx.x * 32, r0 = blockIdx.y * 32;
  int tx = threadIdx.x & 31, ty = threadIdx.x >> 5;  // 256 threads: 32x8
#pragma unroll
  for (int i = 0; i < 32; i += 8)
    tile[ty + i][tx] = W[(size_t)(r0 + ty + i) * H3 + c0 + tx];
  __syncthreads();
#pragma unroll
  for (int i = 0; i < 32; i += 8)
    WT[(size_t)(c0 + ty + i) * HH + r0 + tx] = __float2bfloat16(tile[tx][ty + i]);
}

// ---------------- gi = x @ Wi + bi  (bf16 MFMA, 128x128 tile, BK=32) ----------------

template <bool GIF32>
__global__ __launch_bounds__(256, 2) void k_gemm_gi(
    const __hip_bfloat16* __restrict__ A,   // [16384][1024] x bf16
    const __hip_bfloat16* __restrict__ Bt,  // [3072][1024]  Wi^T bf16
    const float* __restrict__ bi,           // [3072]
    void* __restrict__ gi)                  // [16384][3072] f32 or bf16
{
  __shared__ __align__(16) __hip_bfloat16 As[128 * 32];
  __shared__ __align__(16) __hip_bfloat16 Bs[128 * 32];
  const int bid = blockIdx.x;
  const int mt = bid / 24, nt = bid % 24;
  const int m0 = mt * 128, n0 = nt * 128;
  const int tid = threadIdx.x, lane = tid & 63, w = tid >> 6;
  const int wm = w & 1, wn = w >> 1;

  f32x4 acc[4][4];
#pragma unroll
  for (int ai = 0; ai < 4; ++ai)
#pragma unroll
    for (int bj = 0; bj < 4; ++bj) acc[ai][bj] = (f32x4){0.f, 0.f, 0.f, 0.f};

  for (int k0 = 0; k0 < HH; k0 += 32) {
#pragma unroll
    for (int i = 0; i < 2; ++i) {
      const int c = w + i * 4;          // 1KB chunk id, wave-uniform
      const int idx = c * 64 + lane;    // 16B unit id
      const int row = idx >> 2, slot = idx & 3;
      __builtin_amdgcn_global_load_lds(
          (const __attribute__((address_space(1))) void*)(A + (size_t)(m0 + row) * HH + k0 + slot * 8),
          (__attribute__((address_space(3))) void*)(As + c * 512), 16, 0, 0);
      __builtin_amdgcn_global_load_lds(
          (const __attribute__((address_space(1))) void*)(Bt + (size_t)(n0 + row) * HH + k0 + slot * 8),
          (__attribute__((address_space(3))) void*)(Bs + c * 512), 16, 0, 0);
    }
    __syncthreads();
    s16x8 af[4], bf[4];
#pragma unroll
    for (int ai = 0; ai < 4; ++ai) {
      int r = wm * 64 + ai * 16 + (lane & 15);
      af[ai] = *reinterpret_cast<const s16x8*>(As + r * 32 + (lane >> 4) * 8);
    }
#pragma unroll
    for (int bj = 0; bj < 4; ++bj) {
      int r = wn * 64 + bj * 16 + (lane & 15);
      bf[bj] = *reinterpret_cast<const s16x8*>(Bs + r * 32 + (lane >> 4) * 8);
    }
#pragma unroll
    for (int ai = 0; ai < 4; ++ai)
#pragma unroll
      for (int bj = 0; bj < 4; ++bj) acc[ai][bj] = mfma16(af[ai], bf[bj], acc[ai][bj]);
    __syncthreads();
  }

#pragma unroll
  for (int ai = 0; ai < 4; ++ai) {
#pragma unroll
    for (int reg = 0; reg < 4; ++reg) {
      const size_t row = (size_t)m0 + wm * 64 + ai * 16 + (lane >> 4) * 4 + reg;
#pragma unroll
      for (int bj = 0; bj < 4; ++bj) {
        const int col = n0 + wn * 64 + bj * 16 + (lane & 15);
        float v = acc[ai][bj][reg] + bi[col];
        if (GIF32)
          reinterpret_cast<float*>(gi)[row * H3 + col] = v;
        else
          reinterpret_cast<__hip_bfloat16*>(gi)[row * H3 + col] = __float2bfloat16(v);
      }
    }
  }
}

// ---------------- persistent step kernel ----------------

#define LD8(p) __hip_atomic_load((p), __ATOMIC_RELAXED, __HIP_MEMORY_SCOPE_AGENT)

// load 16 consecutive 8B words (chunk c covers kk in [c*8, c*8+8))
#define LOADC(W, c)                                        \
  do {                                                     \
    _Pragma("unroll") for (int i_ = 0; i_ < 8; ++i_) {     \
      W[2 * i_ + 0] = LD8(arow + (c) * 64 + i_ * 8 + 0);   \
      W[2 * i_ + 1] = LD8(arow + (c) * 64 + i_ * 8 + 1);   \
    }                                                      \
  } while (0)

// validate chunk against sentinel; reload whole chunk while any word bad
#define CHECKR(W, c)                                                         \
  do {                                                                       \
    int g_ = 0;                                                              \
    for (;;) {                                                               \
      unsigned bad_ = 0;                                                     \
      _Pragma("unroll") for (int i_ = 0; i_ < 16; ++i_)                      \
          bad_ |= (unsigned)(W[i_] == ~0ull);                                \
      if (!__any((int)bad_) || ++g_ >= (1 << 20)) break;                     \
      LOADC(W, c);                                                           \
    }                                                                        \
  } while (0)

// consume chunk: 8 K-blocks x 3 gate MFMAs
#define MFMAC(W, c)                                                          \
  do {                                                                       \
    _Pragma("unroll") for (int i_ = 0; i_ < 8; ++i_) {                       \
      const int kk_ = (c) * 8 + i_;                                          \
      union { ull q[2]; s16x8 v; } u_;                                       \
      u_.q[0] = W[2 * i_ + 0] & amask;                                       \
      u_.q[1] = W[2 * i_ + 1] & amask;                                       \
      const int kb_ = kk_ * 64 + (lane >> 4) * 16;                           \
      s16x8 b0_ = *reinterpret_cast<const s16x8*>(bbase + rb0 + (kb_ ^ xsw)); \
      s16x8 b1_ = *reinterpret_cast<const s16x8*>(bbase + rb1 + (kb_ ^ xsw)); \
      s16x8 b2_ = *reinterpret_cast<const s16x8*>(bbase + rb2 + (kb_ ^ xsw)); \
      aR = mfma16(u_.v, b0_, aR);                                            \
      aZ = mfma16(u_.v, b1_, aZ);                                            \
      aN = mfma16(u_.v, b2_, aN);                                            \
    }                                                                        \
  } while (0)

// 256 WGs x 64 threads. 4 groups (16 batches each) x 64 WGs (16 j-cols each).
// Wh^T slice (48 cols x 1024 k, 96 KiB) LDS-resident with XOR swizzle.
template <bool GIF32>
__global__ __launch_bounds__(64, 1) void k_gru(
    const void* __restrict__ gi_,
    const int* __restrict__ resets,   // [256][64]
    const float* __restrict__ h0,     // [64][1024]
    const float* __restrict__ bn,     // [1024]
    const __hip_bfloat16* __restrict__ WhT,  // [3072][1024]
    __hip_bfloat16* hseq,                    // [257][4][16][1024] sentinel-filled
    float* __restrict__ out)                 // [64*1024 hfinal | 256*64*1024 ys]
{
  __shared__ __align__(16) __hip_bfloat16 Bsh[48 * 1024];  // 96 KiB
  __shared__ __align__(8) __hip_bfloat16 hsh[16][16];      // 512 B transpose buffer
  const int wg = blockIdx.x, lane = threadIdx.x;
  const int g = (wg & 7) >> 1;                // XCD-pair -> group (perf heuristic only)
  const int s = ((wg >> 3) << 1) | (wg & 1);  // 0..63 within group
  const int bg0 = g * 16, j0 = s * 16;

  // stage Wh^T slice into LDS, XOR-swizzled: data(row, slot16B) at byte
  // row*2048 + ((slot*16) ^ ((row&7)<<4))
  for (int cch = lane; cch < 48 * 128; cch += 64) {
    const int row = cch >> 7, slot = cch & 127;
    const int gate = row >> 4, jj = row & 15;
    u32x4 v = *reinterpret_cast<const u32x4*>(WhT + (size_t)(gate * HH + j0 + jj) * HH + slot * 8);
    const int byte = row * 2048 + ((slot * 16) ^ ((row & 7) << 4));
    *reinterpret_cast<u32x4*>(reinterpret_cast<char*>(Bsh) + byte) = v;
  }

  const int jl = lane & 15;         // local j (C col)
  const int bh = (lane >> 4) * 4;   // C row base (batch-local)
  const int prow = lane >> 2, pq = (lane & 3) * 4;  // publish layout: 8B per lane

  float hp[4];
#pragma unroll
  for (int r = 0; r < 4; ++r) hp[r] = h0[(size_t)(bg0 + bh + r) * HH + j0 + jl];

  // publish slot 0 (= h_{-1}): LDS transpose -> coalesced 8B atomic stores
#pragma unroll
  for (int r = 0; r < 4; ++r) hsh[bh + r][jl] = __float2bfloat16(hp[r]);
  __syncthreads();
  {
    ull pv = *reinterpret_cast<const ull*>(&hsh[prow][pq]);
    __hip_atomic_store(reinterpret_cast<ull*>(hseq + (size_t)g * 16384 + prow * HH + j0 + pq),
                       pv, __ATOMIC_RELAXED, __HIP_MEMORY_SCOPE_AGENT);
  }

  const int al = lane & 15;           // A-fragment batch row (group-local)
  const int koff = (lane >> 4) * 8;   // A-fragment k sub-offset (elements)
  const char* bbase = reinterpret_cast<const char*>(Bsh);
  const int xsw = (jl & 7) << 4;
  const int rb0 = jl * 2048, rb1 = (16 + jl) * 2048, rb2 = (32 + jl) * 2048;
  const int j = j0 + jl;
  const float bnj = bn[j];

  // prologue: prefetch step-0 gi / resets
  float girC[4], gizC[4], ginC[4];
  int rstEC[4], rstAC;
#pragma unroll
  for (int r = 0; r < 4; ++r) {
    const int b = bg0 + bh + r;
    rstEC[r] = resets[b];
    if (GIF32) {
      const float* grow = reinterpret_cast<const float*>(gi_) + (size_t)b * H3;
      girC[r] = grow[j]; gizC[r] = grow[HH + j]; ginC[r] = grow[2 * HH + j];
    } else {
      const __hip_bfloat16* grow = reinterpret_cast<const __hip_bfloat16*>(gi_) + (size_t)b * H3;
      girC[r] = __bfloat162float(grow[j]);
      gizC[r] = __bfloat162float(grow[HH + j]);
      ginC[r] = __bfloat162float(grow[2 * HH + j]);
    }
  }
  rstAC = resets[bg0 + al];

  for (int t = 0; t < TT; ++t) {
    // prefetch NEXT step's gi / resets; latency hides under this step's poll
    const int tn = (t + 1 < TT) ? t + 1 : t;
    float girN[4], gizN[4], ginN[4];
    int rstEN[4];
#pragma unroll
    for (int r = 0; r < 4; ++r) {
      const int b = bg0 + bh + r;
      rstEN[r] = resets[tn * BB + b];
      if (GIF32) {
        const float* grow = reinterpret_cast<const float*>(gi_) + (size_t)(tn * BB + b) * H3;
        girN[r] = grow[j]; gizN[r] = grow[HH + j]; ginN[r] = grow[2 * HH + j];
      } else {
        const __hip_bfloat16* grow =
            reinterpret_cast<const __hip_bfloat16*>(gi_) + (size_t)(tn * BB + b) * H3;
        girN[r] = __bfloat162float(grow[j]);
        gizN[r] = __bfloat162float(grow[HH + j]);
        ginN[r] = __bfloat162float(grow[2 * HH + j]);
      }
    }
    const int rstAN = resets[tn * BB + bg0 + al];

    const ull amask = rstAC ? 0ull : ~0ull;

    // poll-load h_{t-1} in 4 chunks of 16 words, 2-deep pipelined
    const __hip_bfloat16* rd = hseq + (size_t)t * 65536 + g * 16384;
    const ull* arow = reinterpret_cast<const ull*>(rd + al * HH + koff);
    f32x4 aR = {0.f, 0.f, 0.f, 0.f}, aZ = {0.f, 0.f, 0.f, 0.f}, aN = {0.f, 0.f, 0.f, 0.f};
    {
      ull wA[16], wB[16];
      LOADC(wA, 0);
      LOADC(wB, 1);
      CHECKR(wA, 0); MFMAC(wA, 0); LOADC(wA, 2);
      CHECKR(wB, 1); MFMAC(wB, 1); LOADC(wB, 3);
      CHECKR(wA, 2); MFMAC(wA, 2);
      CHECKR(wB, 3); MFMAC(wB, 3);
    }

    float hnew[4];
#pragma unroll
    for (int r = 0; r < 4; ++r) {
      const float hprev = rstEC[r] ? 0.f : hp[r];
      const float rg = fast_sigmoid(girC[r] + aR[r]);
      const float zg = fast_sigmoid(gizC[r] + aZ[r]);
      const float ng = fast_tanh(ginC[r] + rg * (aN[r] + bnj));
      hnew[r] = (1.0f - zg) * ng + zg * hprev;
      hp[r] = hnew[r];
    }

    // publish h_t to slot t+1: LDS transpose -> coalesced 8B atomic stores
    __syncthreads();  // hsh free (previous publish read done)
#pragma unroll
    for (int r = 0; r < 4; ++r) hsh[bh + r][jl] = __float2bfloat16(hnew[r]);
    __syncthreads();
    {
      ull pv = *reinterpret_cast<const ull*>(&hsh[prow][pq]);
      __hip_atomic_store(
          reinterpret_cast<ull*>(hseq + (size_t)(t + 1) * 65536 + g * 16384 + prow * HH + j0 + pq),
          pv, __ATOMIC_RELAXED, __HIP_MEMORY_SCOPE_AGENT);
    }

    // ys writes after the publish: off the inter-WG critical path
    float* ys = out + 65536 + (size_t)t * 65536;
#pragma unroll
    for (int r = 0; r < 4; ++r)
      __builtin_nontemporal_store(hnew[r], &ys[(size_t)(bg0 + bh + r) * HH + j]);

    // rotate prefetched operands (compiler places the waitcnt here, late)
#pragma unroll
    for (int r = 0; r < 4; ++r) {
      girC[r] = girN[r]; gizC[r] = gizN[r]; ginC[r] = ginN[r];
      rstEC[r] = rstEN[r];
    }
    rstAC = rstAN;
  }

#pragma unroll
  for (int r = 0; r < 4; ++r)
    out[(size_t)(bg0 + bh + r) * HH + j0 + jl] = hp[r];
}

// ---------------- launch ----------------

extern "C" void kernel_launch(void* const* d_in, const int* in_sizes, int n_in,
                              void* d_out, int out_size, void* d_ws, size_t ws_size,
                              hipStream_t stream) {
  const float* x      = (const float*)d_in[0];  // [256,64,1024]
  const int* resets   = (const int*)d_in[1];    // [256,64]
  const float* h0     = (const float*)d_in[2];  // [64,1024]
  const float* Wi     = (const float*)d_in[3];  // [1024,3072]
  const float* bi     = (const float*)d_in[4];  // [3072]
  const float* Wh     = (const float*)d_in[5];  // [1024,3072]
  const float* bn     = (const float*)d_in[6];  // [1024]
  (void)in_sizes; (void)n_in; (void)out_size;

  char* ws = (char*)d_ws;
  // region0: xb [16384][1024] bf16 (33,554,432 B), dead after gemm, then
  //          reused as hseq [257][4][16][1024] bf16 (33,685,504 B)
  __hip_bfloat16* xb   = (__hip_bfloat16*)(ws);
  __hip_bfloat16* hseq = (__hip_bfloat16*)(ws);
  __hip_bfloat16* WiT  = (__hip_bfloat16*)(ws + 33685504);  // 6,291,456 B
  __hip_bfloat16* WhT  = (__hip_bfloat16*)(ws + 39976960);  // 6,291,456 B
  void* gi             = (void*)(ws + 46268416);

  const bool gif32 = ws_size >= 46268416ull + (size_t)16384 * 3072 * 4;

  k_cvt_x<<<16384, 256, 0, stream>>>(x, xb, TT * BB * HH);
  k_transpose_w<<<dim3(96, 32), 256, 0, stream>>>(Wi, WiT);
  k_transpose_w<<<dim3(96, 32), 256, 0, stream>>>(Wh, WhT);
  if (gif32) {
    k_gemm_gi<true><<<3072, 256, 0, stream>>>(xb, WiT, bi, gi);
    // xb dead; sentinel-fill hseq (0xFF = -NaN bf16 words)
    hipMemsetAsync(hseq, 0xFF, 33685504, stream);
    k_gru<true><<<256, 64, 0, stream>>>(gi, resets, h0, bn, WhT, hseq, (float*)d_out);
  } else {
    k_gemm_gi<false><<<3072, 256, 0, stream>>>(xb, WiT, bi, gi);
    hipMemsetAsync(hseq, 0xFF, 33685504, stream);
    k_gru<false><<<256, 64, 0, stream>>>(gi, resets, h0, bn, WhT, hseq, (float*)d_out);
  }
}

// Round 5
// 1413.188 us; speedup vs baseline: 2.8039x; 1.1264x over previous
//
#include <hip/hip_runtime.h>
#include <hip/hip_bf16.h>
#include <cstdint>

// GRU scan: T=256, B=64, H=1024.
// gi = x@Wi + bi precomputed with one bf16 MFMA GEMM; then a persistent
// 256-WG x 256-thread kernel walks 256 sequential steps with Wh^T resident
// in LDS. Cross-WG h exchange: sentinel-data handshake (no flags, no ACK):
// h_t goes to a fresh slot of a [257][64][1024] bf16 sequence buffer
// (sentinel 0xFF = -NaN bf16, unproducible from finite arithmetic).
// Each of the 4 waves polls+consumes one 16-word chunk IN PARALLEL (canary
// word first, then full chunk + verify); partial MFMA sums reduce via LDS.

#define TT 256
#define BB 64
#define HH 1024
#define H3 3072

typedef __attribute__((ext_vector_type(8))) short s16x8;
typedef __attribute__((ext_vector_type(4))) float f32x4;
typedef __attribute__((ext_vector_type(4))) unsigned int u32x4;
typedef unsigned long long ull;

__device__ __forceinline__ float fast_sigmoid(float x) {
  float e = __expf(-fabsf(x));
  float s = 1.0f / (1.0f + e);
  return x >= 0.0f ? s : 1.0f - s;
}
__device__ __forceinline__ float fast_tanh(float x) {
  float e = __expf(-2.0f * fabsf(x));
  float t = (1.0f - e) / (1.0f + e);
  return x >= 0.0f ? t : -t;
}
__device__ __forceinline__ f32x4 mfma16(s16x8 a, s16x8 b, f32x4 c) {
  return __builtin_amdgcn_mfma_f32_16x16x32_bf16(a, b, c, 0, 0, 0);
}

#define LD8(p) __hip_atomic_load((p), __ATOMIC_RELAXED, __HIP_MEMORY_SCOPE_AGENT)

// ---------------- conversion kernels ----------------

__global__ void k_cvt_x(const float* __restrict__ x, __hip_bfloat16* __restrict__ xb, int n) {
  int i = (blockIdx.x * blockDim.x + threadIdx.x) * 4;
  if (i + 3 < n) {
    float4 v = *reinterpret_cast<const float4*>(x + i);
    xb[i + 0] = __float2bfloat16(v.x);
    xb[i + 1] = __float2bfloat16(v.y);
    xb[i + 2] = __float2bfloat16(v.z);
    xb[i + 3] = __float2bfloat16(v.w);
  }
}

// W [1024][3072] f32 -> WT [3072][1024] bf16
__global__ void k_transpose_w(const float* __restrict__ W, __hip_bfloat16* __restrict__ WT) {
  __shared__ float tile[32][33];
  int c0 = blockIdx.x * 32, r0 = blockIdx.y * 32;
  int tx = threadIdx.x & 31, ty = threadIdx.x >> 5;  // 256 threads: 32x8
#pragma unroll
  for (int i = 0; i < 32; i += 8)
    tile[ty + i][tx] = W[(size_t)(r0 + ty + i) * H3 + c0 + tx];
  __syncthreads();
#pragma unroll
  for (int i = 0; i < 32; i += 8)
    WT[(size_t)(c0 + ty + i) * HH + r0 + tx] = __float2bfloat16(tile[tx][ty + i]);
}

// ---------------- gi = x @ Wi + bi  (bf16 MFMA, 128x128 tile, BK=32) ----------------

template <bool GIF32>
__global__ __launch_bounds__(256, 2) void k_gemm_gi(
    const __hip_bfloat16* __restrict__ A,   // [16384][1024] x bf16
    const __hip_bfloat16* __restrict__ Bt,  // [3072][1024]  Wi^T bf16
    const float* __restrict__ bi,           // [3072]
    void* __restrict__ gi)                  // [16384][3072] f32 or bf16
{
  __shared__ __align__(16) __hip_bfloat16 As[128 * 32];
  __shared__ __align__(16) __hip_bfloat16 Bs[128 * 32];
  const int bid = blockIdx.x;
  const int mt = bid / 24, nt = bid % 24;
  const int m0 = mt * 128, n0 = nt * 128;
  const int tid = threadIdx.x, lane = tid & 63, w = tid >> 6;
  const int wm = w & 1, wn = w >> 1;

  f32x4 acc[4][4];
#pragma unroll
  for (int ai = 0; ai < 4; ++ai)
#pragma unroll
    for (int bj = 0; bj < 4; ++bj) acc[ai][bj] = (f32x4){0.f, 0.f, 0.f, 0.f};

  for (int k0 = 0; k0 < HH; k0 += 32) {
#pragma unroll
    for (int i = 0; i < 2; ++i) {
      const int c = w + i * 4;          // 1KB chunk id, wave-uniform
      const int idx = c * 64 + lane;    // 16B unit id
      const int row = idx >> 2, slot = idx & 3;
      __builtin_amdgcn_global_load_lds(
          (const __attribute__((address_space(1))) void*)(A + (size_t)(m0 + row) * HH + k0 + slot * 8),
          (__attribute__((address_space(3))) void*)(As + c * 512), 16, 0, 0);
      __builtin_amdgcn_global_load_lds(
          (const __attribute__((address_space(1))) void*)(Bt + (size_t)(n0 + row) * HH + k0 + slot * 8),
          (__attribute__((address_space(3))) void*)(Bs + c * 512), 16, 0, 0);
    }
    __syncthreads();
    s16x8 af[4], bf[4];
#pragma unroll
    for (int ai = 0; ai < 4; ++ai) {
      int r = wm * 64 + ai * 16 + (lane & 15);
      af[ai] = *reinterpret_cast<const s16x8*>(As + r * 32 + (lane >> 4) * 8);
    }
#pragma unroll
    for (int bj = 0; bj < 4; ++bj) {
      int r = wn * 64 + bj * 16 + (lane & 15);
      bf[bj] = *reinterpret_cast<const s16x8*>(Bs + r * 32 + (lane >> 4) * 8);
    }
#pragma unroll
    for (int ai = 0; ai < 4; ++ai)
#pragma unroll
      for (int bj = 0; bj < 4; ++bj) acc[ai][bj] = mfma16(af[ai], bf[bj], acc[ai][bj]);
    __syncthreads();
  }

#pragma unroll
  for (int ai = 0; ai < 4; ++ai) {
#pragma unroll
    for (int reg = 0; reg < 4; ++reg) {
      const size_t row = (size_t)m0 + wm * 64 + ai * 16 + (lane >> 4) * 4 + reg;
#pragma unroll
      for (int bj = 0; bj < 4; ++bj) {
        const int col = n0 + wn * 64 + bj * 16 + (lane & 15);
        float v = acc[ai][bj][reg] + bi[col];
        if (GIF32)
          reinterpret_cast<float*>(gi)[row * H3 + col] = v;
        else
          reinterpret_cast<__hip_bfloat16*>(gi)[row * H3 + col] = __float2bfloat16(v);
      }
    }
  }
}

// ---------------- persistent step kernel ----------------

// 256 WGs x 256 threads (4 waves). 4 groups (16 batches) x 64 WGs (16 j-cols).
// Wh^T slice (48 rows x 1024 k, 96 KiB) LDS-resident with XOR swizzle.
// Wave w polls+MFMAs K-chunk w (kk in [8w, 8w+8)); wave 0 reduces+publishes.
template <bool GIF32>
__global__ __launch_bounds__(256, 1) void k_gru(
    const void* __restrict__ gi_,
    const int* __restrict__ resets,   // [256][64]
    const float* __restrict__ h0,     // [64][1024]
    const float* __restrict__ bn,     // [1024]
    const __hip_bfloat16* __restrict__ WhT,  // [3072][1024]
    __hip_bfloat16* hseq,                    // [257][64][1024] sentinel-filled
    float* __restrict__ out)                 // [64*1024 hfinal | 256*64*1024 ys]
{
  __shared__ __align__(16) __hip_bfloat16 Bsh[48 * 1024];  // 96 KiB
  __shared__ __align__(16) f32x4 part[2][4][3][64];        // 24 KiB partials
  __shared__ __align__(8) __hip_bfloat16 hsh[16][16];      // 512 B transpose
  const int tid = threadIdx.x;
  const int wave = tid >> 6, lane = tid & 63;
  const int wg = blockIdx.x;
  const int g = (wg & 7) >> 1;                // XCD-pair -> group (perf heuristic only)
  const int s = ((wg >> 3) << 1) | (wg & 1);  // 0..63 within group
  const int bg0 = g * 16, j0 = s * 16;

  // stage Wh^T slice into LDS, XOR-swizzled: data(row, slot16B) at byte
  // row*2048 + ((slot*16) ^ ((row&7)<<4))
  for (int cch = tid; cch < 48 * 128; cch += 256) {
    const int row = cch >> 7, slot = cch & 127;
    const int gate = row >> 4, jj = row & 15;
    u32x4 v = *reinterpret_cast<const u32x4*>(WhT + (size_t)(gate * HH + j0 + jj) * HH + slot * 8);
    const int byte = row * 2048 + ((slot * 16) ^ ((row & 7) << 4));
    *reinterpret_cast<u32x4*>(reinterpret_cast<char*>(Bsh) + byte) = v;
  }

  const int jl = lane & 15;         // local j (C col)
  const int bh = (lane >> 4) * 4;   // C row base (batch-local)
  const int prow = lane >> 2, pq = (lane & 3) * 4;  // publish layout: 8B/lane
  const int al = lane & 15;         // A-fragment batch row (group-local)
  const int koff = (lane >> 4) * 8; // A-fragment k sub-offset (elements)
  const int j = j0 + jl;

  const char* bbase = reinterpret_cast<const char*>(Bsh);
  const int xsw = (jl & 7) << 4;
  const int rb0 = jl * 2048, rb1 = (16 + jl) * 2048, rb2 = (32 + jl) * 2048;

  float hp[4];
  float girC[4], gizC[4], ginC[4];
  int rstEC[4];
  float bnj = 0.f;

  if (wave == 0) {
    bnj = bn[j];
#pragma unroll
    for (int r = 0; r < 4; ++r) hp[r] = h0[(size_t)(bg0 + bh + r) * HH + j0 + jl];
    // publish slot 0 (= h_{-1}): LDS transpose -> coalesced 8B atomic stores
#pragma unroll
    for (int r = 0; r < 4; ++r) hsh[bh + r][jl] = __float2bfloat16(hp[r]);
    ull pv = *reinterpret_cast<const ull*>(&hsh[prow][pq]);
    __hip_atomic_store(reinterpret_cast<ull*>(hseq + (size_t)g * 16384 + prow * HH + j0 + pq),
                       pv, __ATOMIC_RELAXED, __HIP_MEMORY_SCOPE_AGENT);
    // prologue: step-0 gi / resets
#pragma unroll
    for (int r = 0; r < 4; ++r) {
      const int b = bg0 + bh + r;
      rstEC[r] = resets[b];
      if (GIF32) {
        const float* grow = reinterpret_cast<const float*>(gi_) + (size_t)b * H3;
        girC[r] = grow[j]; gizC[r] = grow[HH + j]; ginC[r] = grow[2 * HH + j];
      } else {
        const __hip_bfloat16* grow = reinterpret_cast<const __hip_bfloat16*>(gi_) + (size_t)b * H3;
        girC[r] = __bfloat162float(grow[j]);
        gizC[r] = __bfloat162float(grow[HH + j]);
        ginC[r] = __bfloat162float(grow[2 * HH + j]);
      }
    }
  }
  __syncthreads();  // Bsh staged

  for (int t = 0; t < TT; ++t) {
    const int rstA = resets[t * BB + bg0 + al];  // hidden under the spin
    const __hip_bfloat16* rd = hseq + (size_t)t * 65536 + g * 16384;
    const ull* ch = reinterpret_cast<const ull*>(rd + al * HH + koff) + wave * 64;

    // canary spin: one 8B word per lane (last word of my chunk)
    {
      int gq = 0;
      ull can;
      do {
        can = LD8(ch + 57);
      } while (__any((int)(can == ~0ull)) && ++gq < (1 << 22));
    }
    // full chunk load + verify (stragglers rare after canary clears)
    ull w[16];
#pragma unroll
    for (int i = 0; i < 8; ++i) {
      w[2 * i + 0] = LD8(ch + i * 8 + 0);
      w[2 * i + 1] = LD8(ch + i * 8 + 1);
    }
    {
      int gq = 0;
      for (;;) {
        unsigned bad = 0;
#pragma unroll
        for (int i = 0; i < 16; ++i) bad |= (unsigned)(w[i] == ~0ull);
        if (!__any((int)bad) || ++gq >= (1 << 20)) break;
#pragma unroll
        for (int i = 0; i < 8; ++i) {
          w[2 * i + 0] = LD8(ch + i * 8 + 0);
          w[2 * i + 1] = LD8(ch + i * 8 + 1);
        }
      }
    }

    // 24 partial MFMAs for this wave's K-range
    const ull amask = rstA ? 0ull : ~0ull;
    f32x4 aR = {0.f, 0.f, 0.f, 0.f}, aZ = {0.f, 0.f, 0.f, 0.f}, aN = {0.f, 0.f, 0.f, 0.f};
#pragma unroll
    for (int i = 0; i < 8; ++i) {
      const int kk = wave * 8 + i;
      union { ull q[2]; s16x8 v; } u;
      u.q[0] = w[2 * i + 0] & amask;
      u.q[1] = w[2 * i + 1] & amask;
      const int kb = kk * 64 + (lane >> 4) * 16;
      s16x8 b0 = *reinterpret_cast<const s16x8*>(bbase + rb0 + (kb ^ xsw));
      s16x8 b1 = *reinterpret_cast<const s16x8*>(bbase + rb1 + (kb ^ xsw));
      s16x8 b2 = *reinterpret_cast<const s16x8*>(bbase + rb2 + (kb ^ xsw));
      aR = mfma16(u.v, b0, aR);
      aZ = mfma16(u.v, b1, aZ);
      aN = mfma16(u.v, b2, aN);
    }

    const int p = t & 1;
    part[p][wave][0][lane] = aR;
    part[p][wave][1][lane] = aZ;
    part[p][wave][2][lane] = aN;
    __syncthreads();  // partials visible (parity double-buffer -> one barrier)

    if (wave == 0) {
      f32x4 sR = part[p][0][0][lane], sZ = part[p][0][1][lane], sN = part[p][0][2][lane];
#pragma unroll
      for (int ww = 1; ww < 4; ++ww) {
        sR += part[p][ww][0][lane];
        sZ += part[p][ww][1][lane];
        sN += part[p][ww][2][lane];
      }
      float hnew[4];
#pragma unroll
      for (int r = 0; r < 4; ++r) {
        const float hprev = rstEC[r] ? 0.f : hp[r];
        const float rg = fast_sigmoid(girC[r] + sR[r]);
        const float zg = fast_sigmoid(gizC[r] + sZ[r]);
        const float ng = fast_tanh(ginC[r] + rg * (sN[r] + bnj));
        hnew[r] = (1.0f - zg) * ng + zg * hprev;
        hp[r] = hnew[r];
      }
      // publish h_t to slot t+1: LDS transpose -> coalesced 8B atomic stores
#pragma unroll
      for (int r = 0; r < 4; ++r) hsh[bh + r][jl] = __float2bfloat16(hnew[r]);
      ull pv = *reinterpret_cast<const ull*>(&hsh[prow][pq]);
      __hip_atomic_store(
          reinterpret_cast<ull*>(hseq + (size_t)(t + 1) * 65536 + g * 16384 + prow * HH + j0 + pq),
          pv, __ATOMIC_RELAXED, __HIP_MEMORY_SCOPE_AGENT);

      // ys writes after the publish: off the inter-WG critical path
      float* ys = out + 65536 + (size_t)t * 65536;
#pragma unroll
      for (int r = 0; r < 4; ++r)
        __builtin_nontemporal_store(hnew[r], &ys[(size_t)(bg0 + bh + r) * HH + j]);

      // prefetch next step's gi / resets; consumed after next barrier
      const int tn = (t + 1 < TT) ? t + 1 : t;
#pragma unroll
      for (int r = 0; r < 4; ++r) {
        const int b = bg0 + bh + r;
        rstEC[r] = resets[tn * BB + b];
        if (GIF32) {
          const float* grow = reinterpret_cast<const float*>(gi_) + (size_t)(tn * BB + b) * H3;
          girC[r] = grow[j]; gizC[r] = grow[HH + j]; ginC[r] = grow[2 * HH + j];
        } else {
          const __hip_bfloat16* grow =
              reinterpret_cast<const __hip_bfloat16*>(gi_) + (size_t)(tn * BB + b) * H3;
          girC[r] = __bfloat162float(grow[j]);
          gizC[r] = __bfloat162float(grow[HH + j]);
          ginC[r] = __bfloat162float(grow[2 * HH + j]);
        }
      }
    }
  }

  if (wave == 0) {
#pragma unroll
    for (int r = 0; r < 4; ++r)
      out[(size_t)(bg0 + bh + r) * HH + j0 + jl] = hp[r];
  }
}

// ---------------- launch ----------------

extern "C" void kernel_launch(void* const* d_in, const int* in_sizes, int n_in,
                              void* d_out, int out_size, void* d_ws, size_t ws_size,
                              hipStream_t stream) {
  const float* x      = (const float*)d_in[0];  // [256,64,1024]
  const int* resets   = (const int*)d_in[1];    // [256,64]
  const float* h0     = (const float*)d_in[2];  // [64,1024]
  const float* Wi     = (const float*)d_in[3];  // [1024,3072]
  const float* bi     = (const float*)d_in[4];  // [3072]
  const float* Wh     = (const float*)d_in[5];  // [1024,3072]
  const float* bn     = (const float*)d_in[6];  // [1024]
  (void)in_sizes; (void)n_in; (void)out_size;

  char* ws = (char*)d_ws;
  // region0: xb [16384][1024] bf16 (33,554,432 B), dead after gemm, then
  //          reused as hseq [257][64][1024] bf16 (33,685,504 B)
  __hip_bfloat16* xb   = (__hip_bfloat16*)(ws);
  __hip_bfloat16* hseq = (__hip_bfloat16*)(ws);
  __hip_bfloat16* WiT  = (__hip_bfloat16*)(ws + 33685504);  // 6,291,456 B
  __hip_bfloat16* WhT  = (__hip_bfloat16*)(ws + 39976960);  // 6,291,456 B
  void* gi             = (void*)(ws + 46268416);

  const bool gif32 = ws_size >= 46268416ull + (size_t)16384 * 3072 * 4;

  k_cvt_x<<<16384, 256, 0, stream>>>(x, xb, TT * BB * HH);
  k_transpose_w<<<dim3(96, 32), 256, 0, stream>>>(Wi, WiT);
  k_transpose_w<<<dim3(96, 32), 256, 0, stream>>>(Wh, WhT);
  if (gif32) {
    k_gemm_gi<true><<<3072, 256, 0, stream>>>(xb, WiT, bi, gi);
    // xb dead; sentinel-fill hseq (0xFF = -NaN bf16 words)
    hipMemsetAsync(hseq, 0xFF, 33685504, stream);
    k_gru<true><<<256, 256, 0, stream>>>(gi, resets, h0, bn, WhT, hseq, (float*)d_out);
  } else {
    k_gemm_gi<false><<<3072, 256, 0, stream>>>(xb, WiT, bi, gi);
    hipMemsetAsync(hseq, 0xFF, 33685504, stream);
    k_gru<false><<<256, 256, 0, stream>>>(gi, resets, h0, bn, WhT, hseq, (float*)d_out);
  }
}